// Round 4
// baseline (1118.574 us; speedup 1.0000x reference)
//
#include <hip/hip_runtime.h>
#include <stdint.h>

#define NPTS 16384
#define BATCH 16
#define FPS_N 512
#define NANCH 50
#define TOPK 4
#define NBH 128
#define BALLK 1000

#define FT 1024
#define FPPT (NPTS / FT)   // 16 points per thread

// dynamic LDS for fps: 16384 float2 (xy) + 2*16 u64 reduce slots
#define FPS_XY_BYTES (NPTS * 8)
#define FPS_SMEM (FPS_XY_BYTES + 2 * 16 * 8)

// DPP control codes (within-16-lane row ops)
#define CTRL_XOR1 0xB1   // quad_perm [1,0,3,2]
#define CTRL_XOR2 0x4E   // quad_perm [2,3,0,1]
#define CTRL_ROR4 0x124  // row_ror:4
#define CTRL_ROR8 0x128  // row_ror:8

// u64 max-combine with a DPP-shuffled copy (old=src -> masked lanes identity)
#define DPP_MAX64(v, CTRL) do {                                                   \
  unsigned int _lo = (unsigned int)(v);                                           \
  unsigned int _hi = (unsigned int)((v) >> 32);                                   \
  unsigned int _slo = (unsigned int)__builtin_amdgcn_update_dpp((int)_lo, (int)_lo, CTRL, 0xf, 0xf, false); \
  unsigned int _shi = (unsigned int)__builtin_amdgcn_update_dpp((int)_hi, (int)_hi, CTRL, 0xf, 0xf, false); \
  unsigned long long _o = (((unsigned long long)_shi) << 32) | _slo;              \
  if (_o > (v)) (v) = _o;                                                         \
} while (0)

#define DPP_MIN64(v, CTRL) do {                                                   \
  unsigned int _lo = (unsigned int)(v);                                           \
  unsigned int _hi = (unsigned int)((v) >> 32);                                   \
  unsigned int _slo = (unsigned int)__builtin_amdgcn_update_dpp((int)_lo, (int)_lo, CTRL, 0xf, 0xf, false); \
  unsigned int _shi = (unsigned int)__builtin_amdgcn_update_dpp((int)_hi, (int)_hi, CTRL, 0xf, 0xf, false); \
  unsigned long long _o = (((unsigned long long)_shi) << 32) | _slo;              \
  if (_o < (v)) (v) = _o;                                                         \
} while (0)

// xor-16 via ds_swizzle (valid within each 32-lane half; xor16 stays in-half)
#define SWZ16_MAX64(v) do {                                                       \
  unsigned int _lo = (unsigned int)(v), _hi = (unsigned int)((v) >> 32);          \
  unsigned int _slo = (unsigned int)__builtin_amdgcn_ds_swizzle((int)_lo, 0x401f);\
  unsigned int _shi = (unsigned int)__builtin_amdgcn_ds_swizzle((int)_hi, 0x401f);\
  unsigned long long _o = (((unsigned long long)_shi) << 32) | _slo;              \
  if (_o > (v)) (v) = _o;                                                         \
} while (0)

#define SWZ16_MIN64(v) do {                                                       \
  unsigned int _lo = (unsigned int)(v), _hi = (unsigned int)((v) >> 32);          \
  unsigned int _slo = (unsigned int)__builtin_amdgcn_ds_swizzle((int)_lo, 0x401f);\
  unsigned int _shi = (unsigned int)__builtin_amdgcn_ds_swizzle((int)_hi, 0x401f);\
  unsigned long long _o = (((unsigned long long)_shi) << 32) | _slo;              \
  if (_o < (v)) (v) = _o;                                                         \
} while (0)

#define SHF32_MAX64(v) do {                                                       \
  unsigned long long _o = __shfl_xor((v), 32, 64);                                \
  if (_o > (v)) (v) = _o;                                                         \
} while (0)

#define SHF32_MIN64(v) do {                                                       \
  unsigned long long _o = __shfl_xor((v), 32, 64);                                \
  if (_o < (v)) (v) = _o;                                                         \
} while (0)

// ---------------- FPS: one block per batch, 511 serial argmax steps ----------
// Coordinates x,y live in LDS (structural residency -- the compiler cannot sink
// LDS reads back to global); z + dist stay in registers (32 regs, under any cap).
__global__ __launch_bounds__(FT) void fps_kernel(const float* __restrict__ pts,
                                                 int* __restrict__ fps_idx) {
  extern __shared__ char smem[];
  float2* __restrict__ xy = (float2*)smem;
  unsigned long long* __restrict__ waveres =
      (unsigned long long*)(smem + FPS_XY_BYTES);  // [2][16]

  const int b = blockIdx.x;
  const int tid = threadIdx.x;
  const float* __restrict__ px = pts + (size_t)b * 3 * NPTS;
  const float* __restrict__ py = px + NPTS;
  const float* __restrict__ pz = py + NPTS;

  float z[FPPT], dist[FPPT];
#pragma unroll
  for (int k = 0; k < FPPT; ++k) {
    const int i = tid + (k << 10);
    const float X = px[i], Y = py[i];
    z[k] = pz[i];
    dist[k] = 1e10f;
    xy[i] = make_float2(X, Y);
  }
  if (tid == 0) fps_idx[b * FPS_N] = 0;
  float bx = px[0], by = py[0], bz = pz[0];
  __syncthreads();  // xy staged

  for (int step = 1; step < FPS_N; ++step) {
    float bd = -1.0f;
    int bk = 0;
#pragma unroll
    for (int k = 0; k < FPPT; ++k) {
      const float2 P = xy[tid + (k << 10)];  // ds_read_b64
      // match numpy/jax: (x-c)**2 summed, no fma contraction
      const float dx = __fsub_rn(P.x, bx);
      const float dy = __fsub_rn(P.y, by);
      const float dz = __fsub_rn(z[k], bz);
      const float d = __fadd_rn(__fadd_rn(__fmul_rn(dx, dx), __fmul_rn(dy, dy)),
                                __fmul_rn(dz, dz));
      const float dk = fminf(dist[k], d);
      dist[k] = dk;
      if (dk > bd) { bd = dk; bk = k; }  // strict > : lowest k (lowest idx) on ties
    }
    const uint32_t bi = (uint32_t)tid + ((uint32_t)bk << 10);
    unsigned long long key =
        ((unsigned long long)__float_as_uint(bd) << 32) | (uint32_t)(~bi);

    // intra-wave 64-lane max: 4 DPP row steps + xor16 swizzle + xor32 shuffle
    DPP_MAX64(key, CTRL_XOR1);
    DPP_MAX64(key, CTRL_XOR2);
    DPP_MAX64(key, CTRL_ROR4);
    DPP_MAX64(key, CTRL_ROR8);
    SWZ16_MAX64(key);
    SHF32_MAX64(key);

    const int par = step & 1;
    if ((tid & 63) == 0) waveres[par * 16 + (tid >> 6)] = key;
    __syncthreads();

    // lane-parallel 16-way reduce: each lane reads one partial, 4 DPP steps
    unsigned long long g = waveres[par * 16 + (tid & 15)];
    DPP_MAX64(g, CTRL_XOR1);
    DPP_MAX64(g, CTRL_XOR2);
    DPP_MAX64(g, CTRL_ROR4);
    DPP_MAX64(g, CTRL_ROR8);

    const uint32_t widx = ~(uint32_t)g;
    if (tid == 0) fps_idx[b * FPS_N + step] = (int)widx;
    const float2 W = xy[widx];  // centroid xy from LDS (fast broadcast)
    bx = W.x; by = W.y;
    bz = pz[widx];              // z from global (L2-hot), overlaps the LDS read
  }
}

// ---------------- ball-radius counts for the 50 anchors ---------------------
__global__ __launch_bounds__(256) void count_kernel(const float* __restrict__ pts,
                                                    const int* __restrict__ fps_idx,
                                                    int* __restrict__ counts) {
  const int b = blockIdx.y, a = blockIdx.x;
  const int tid = threadIdx.x;
  const float* __restrict__ px = pts + (size_t)b * 3 * NPTS;
  const float* __restrict__ py = px + NPTS;
  const float* __restrict__ pz = py + NPTS;
  const int aidx = fps_idx[b * FPS_N + a];
  const float ax = px[aidx], ay = py[aidx], az = pz[aidx];
  const float asum = __fadd_rn(__fadd_rn(__fmul_rn(ax, ax), __fmul_rn(ay, ay)),
                               __fmul_rn(az, az));
  const float R2 = (float)(0.4 * 0.4);
  int cnt = 0;
  for (int i = tid; i < NPTS; i += 256) {
    const float X = px[i], Y = py[i], Z = pz[i];
    const float dot = __fadd_rn(__fadd_rn(__fmul_rn(ax, X), __fmul_rn(ay, Y)),
                                __fmul_rn(az, Z));
    const float psum = __fadd_rn(__fadd_rn(__fmul_rn(X, X), __fmul_rn(Y, Y)),
                                 __fmul_rn(Z, Z));
    const float d = __fadd_rn(__fadd_rn(__fmul_rn(-2.0f, dot), asum), psum);
    cnt += (d < R2) ? 1 : 0;
  }
#pragma unroll
  for (int off = 32; off > 0; off >>= 1) cnt += __shfl_xor(cnt, off, 64);
  __shared__ int ws[4];
  if ((tid & 63) == 0) ws[tid >> 6] = cnt;
  __syncthreads();
  if (tid == 0) {
    int c = ws[0] + ws[1] + ws[2] + ws[3];
    counts[b * NANCH + a] = c < BALLK ? c : BALLK;
  }
}

// ---------------- top-4 anchors by count (ties -> lowest anchor index) ------
__global__ void top4_kernel(const int* __restrict__ counts,
                            const int* __restrict__ fps_idx,
                            int* __restrict__ top4pt) {
  const int b = threadIdx.x;
  if (b >= BATCH) return;
  unsigned long long used = 0ULL;
  for (int r = 0; r < TOPK; ++r) {
    int bestc = -1, besta = 0;
    for (int a = 0; a < NANCH; ++a) {
      if (used & (1ULL << a)) continue;
      const int c = counts[b * NANCH + a];
      if (c > bestc) { bestc = c; besta = a; }   // strict > keeps lowest index on ties
    }
    used |= 1ULL << besta;
    top4pt[b * TOPK + r] = fps_idx[b * FPS_N + besta];
  }
}

// ---------------- 128-NN per selected anchor, in sorted order ---------------
#define KT 1024
#define KPPT (NPTS / KT)  // 16

__device__ __forceinline__ uint32_t f2key(float f) {
  uint32_t u = __float_as_uint(f);
  return (u & 0x80000000u) ? ~u : (u | 0x80000000u);
}

__global__ __launch_bounds__(KT) void knn_kernel(const float* __restrict__ pts,
                                                 const int* __restrict__ top4pt,
                                                 int* __restrict__ nn_idx) {
  const int b = blockIdx.y, j = blockIdx.x;
  const int tid = threadIdx.x;
  const float* __restrict__ px = pts + (size_t)b * 3 * NPTS;
  const float* __restrict__ py = px + NPTS;
  const float* __restrict__ pz = py + NPTS;
  const int aidx = top4pt[b * TOPK + j];
  const float ax = px[aidx], ay = py[aidx], az = pz[aidx];
  const float asum = __fadd_rn(__fadd_rn(__fmul_rn(ax, ax), __fmul_rn(ay, ay)),
                               __fmul_rn(az, az));
  unsigned long long key[KPPT];
#pragma unroll
  for (int k = 0; k < KPPT; ++k) {
    const int i = tid + k * KT;
    const float X = px[i], Y = py[i], Z = pz[i];
    const float dot = __fadd_rn(__fadd_rn(__fmul_rn(ax, X), __fmul_rn(ay, Y)),
                                __fmul_rn(az, Z));
    const float psum = __fadd_rn(__fadd_rn(__fmul_rn(X, X), __fmul_rn(Y, Y)),
                                 __fmul_rn(Z, Z));
    const float d = __fadd_rn(__fadd_rn(__fmul_rn(-2.0f, dot), asum), psum);
    key[k] = ((unsigned long long)f2key(d) << 32) | (uint32_t)i;  // asc dist, ties asc idx
  }
  __shared__ unsigned long long waveres[2][16];
  for (int t = 0; t < NBH; ++t) {
    // tree-min over the 16 register keys (depth 4, not 15-deep chain)
    unsigned long long m01 = key[0] < key[1] ? key[0] : key[1];
    unsigned long long m23 = key[2] < key[3] ? key[2] : key[3];
    unsigned long long m45 = key[4] < key[5] ? key[4] : key[5];
    unsigned long long m67 = key[6] < key[7] ? key[6] : key[7];
    unsigned long long m89 = key[8] < key[9] ? key[8] : key[9];
    unsigned long long mab = key[10] < key[11] ? key[10] : key[11];
    unsigned long long mcd = key[12] < key[13] ? key[12] : key[13];
    unsigned long long mef = key[14] < key[15] ? key[14] : key[15];
    unsigned long long m0 = m01 < m23 ? m01 : m23;
    unsigned long long m1 = m45 < m67 ? m45 : m67;
    unsigned long long m2 = m89 < mab ? m89 : mab;
    unsigned long long m3 = mcd < mef ? mcd : mef;
    unsigned long long ma = m0 < m1 ? m0 : m1;
    unsigned long long mb = m2 < m3 ? m2 : m3;
    unsigned long long m = ma < mb ? ma : mb;

    DPP_MIN64(m, CTRL_XOR1);
    DPP_MIN64(m, CTRL_XOR2);
    DPP_MIN64(m, CTRL_ROR4);
    DPP_MIN64(m, CTRL_ROR8);
    SWZ16_MIN64(m);
    SHF32_MIN64(m);

    const int par = t & 1;
    if ((tid & 63) == 0) waveres[par][tid >> 6] = m;
    __syncthreads();
    unsigned long long g = waveres[par][tid & 15];
    DPP_MIN64(g, CTRL_XOR1);
    DPP_MIN64(g, CTRL_XOR2);
    DPP_MIN64(g, CTRL_ROR4);
    DPP_MIN64(g, CTRL_ROR8);

    if (tid == 0) nn_idx[(b * TOPK + j) * NBH + t] = (int)(uint32_t)g;
#pragma unroll
    for (int k = 0; k < KPPT; ++k)
      if (key[k] == g) key[k] = ~0ULL;  // remove winner (unique low bits)
  }
}

// ---------------- final gather: [roi, roi, fps_pts] -> out [16,1536,3] ------
__global__ __launch_bounds__(512) void gather_kernel(const float* __restrict__ pts,
                                                     const int* __restrict__ nn_idx,
                                                     const int* __restrict__ fps_idx,
                                                     float* __restrict__ out) {
  const int b = blockIdx.x, t = threadIdx.x;
  const float* __restrict__ px = pts + (size_t)b * 3 * NPTS;
  const float* __restrict__ py = px + NPTS;
  const float* __restrict__ pz = py + NPTS;
  for (int s = t; s < 1536; s += 512) {
    int src;
    if (s < 1024) src = nn_idx[b * 512 + (s & 511)];      // roi1 and roi2 identical
    else          src = fps_idx[b * FPS_N + (s - 1024)];
    float* o = out + ((size_t)b * 1536 + s) * 3;
    o[0] = px[src]; o[1] = py[src]; o[2] = pz[src];
  }
}

extern "C" void kernel_launch(void* const* d_in, const int* in_sizes, int n_in,
                              void* d_out, int out_size, void* d_ws, size_t ws_size,
                              hipStream_t stream) {
  const float* pts = (const float*)d_in[0];   // [16, 3, 16384]
  float* out = (float*)d_out;                 // [16, 1536, 3]
  char* ws = (char*)d_ws;
  int* fps_idx = (int*)(ws);            // 16*512*4 = 32768 B
  int* counts  = (int*)(ws + 32768);    // 16*50*4  =  3200 B
  int* top4pt  = (int*)(ws + 40960);    // 16*4*4   =   256 B
  int* nn_idx  = (int*)(ws + 49152);    // 16*512*4 = 32768 B

  // allow 128KB+ dynamic LDS for fps_kernel (idempotent, host-side, capture-safe)
  hipFuncSetAttribute((const void*)fps_kernel,
                      hipFuncAttributeMaxDynamicSharedMemorySize, FPS_SMEM);

  fps_kernel<<<dim3(BATCH), dim3(FT), FPS_SMEM, stream>>>(pts, fps_idx);
  count_kernel<<<dim3(NANCH, BATCH), dim3(256), 0, stream>>>(pts, fps_idx, counts);
  top4_kernel<<<dim3(1), dim3(64), 0, stream>>>(counts, fps_idx, top4pt);
  knn_kernel<<<dim3(TOPK, BATCH), dim3(KT), 0, stream>>>(pts, top4pt, nn_idx);
  gather_kernel<<<dim3(BATCH), dim3(512), 0, stream>>>(pts, nn_idx, fps_idx, out);
}

// Round 5
// 1072.781 us; speedup vs baseline: 1.0427x; 1.0427x over previous
//
#include <hip/hip_runtime.h>
#include <stdint.h>

#define NPTS 16384
#define BATCH 16
#define FPS_N 512
#define NANCH 50
#define TOPK 4
#define NBH 128
#define BALLK 1000

#define FT 1024
#define FPAIRS 8   // point-pairs per thread (16 pts) for fps

// fps dynamic LDS: X2[8192] float2 + Y2[8192] float2 + waveres[2][16] u64
#define FPS_SMEM (65536 + 65536 + 2 * 16 * 8)

// DPP control codes (within-16-lane row ops)
#define CTRL_XOR1 0xB1   // quad_perm [1,0,3,2]
#define CTRL_XOR2 0x4E   // quad_perm [2,3,0,1]
#define CTRL_ROR4 0x124  // row_ror:4
#define CTRL_ROR8 0x128  // row_ror:8

#define DPP_MAX64(v, CTRL) do {                                                   \
  unsigned int _lo = (unsigned int)(v);                                           \
  unsigned int _hi = (unsigned int)((v) >> 32);                                   \
  unsigned int _slo = (unsigned int)__builtin_amdgcn_update_dpp((int)_lo, (int)_lo, CTRL, 0xf, 0xf, false); \
  unsigned int _shi = (unsigned int)__builtin_amdgcn_update_dpp((int)_hi, (int)_hi, CTRL, 0xf, 0xf, false); \
  unsigned long long _o = (((unsigned long long)_shi) << 32) | _slo;              \
  if (_o > (v)) (v) = _o;                                                         \
} while (0)

#define DPP_MIN64(v, CTRL) do {                                                   \
  unsigned int _lo = (unsigned int)(v);                                           \
  unsigned int _hi = (unsigned int)((v) >> 32);                                   \
  unsigned int _slo = (unsigned int)__builtin_amdgcn_update_dpp((int)_lo, (int)_lo, CTRL, 0xf, 0xf, false); \
  unsigned int _shi = (unsigned int)__builtin_amdgcn_update_dpp((int)_hi, (int)_hi, CTRL, 0xf, 0xf, false); \
  unsigned long long _o = (((unsigned long long)_shi) << 32) | _slo;              \
  if (_o < (v)) (v) = _o;                                                         \
} while (0)

#define SWZ16_MIN64(v) do {                                                       \
  unsigned int _lo = (unsigned int)(v), _hi = (unsigned int)((v) >> 32);          \
  unsigned int _slo = (unsigned int)__builtin_amdgcn_ds_swizzle((int)_lo, 0x401f);\
  unsigned int _shi = (unsigned int)__builtin_amdgcn_ds_swizzle((int)_hi, 0x401f);\
  unsigned long long _o = (((unsigned long long)_shi) << 32) | _slo;              \
  if (_o < (v)) (v) = _o;                                                         \
} while (0)

#define SHF32_MIN64(v) do {                                                       \
  unsigned long long _o = __shfl_xor((v), 32, 64);                                \
  if (_o < (v)) (v) = _o;                                                         \
} while (0)

// ---------------- FPS: one block per batch, 511 serial argmax steps ----------
// VALU-issue-bound at ~1.2GHz power-save clock -> minimize issued instructions:
// packed-f32 distance math (inline asm v_pk_*), value-only DPP reduce (u32),
// index resolution via __ballot + SALU ctz (scalar pipe, free).
__global__ __launch_bounds__(FT, 4) void fps_kernel(const float* __restrict__ pts,
                                                    int* __restrict__ fps_idx) {
  extern __shared__ char smem[];
  float2* __restrict__ X2 = (float2*)smem;                          // 8192 pairs
  float2* __restrict__ Y2 = (float2*)(smem + 65536);                // 8192 pairs
  unsigned long long* __restrict__ waveres =
      (unsigned long long*)(smem + 131072);                         // [2][16]

  const int b = blockIdx.x;
  const int t = threadIdx.x;
  const float* __restrict__ px = pts + (size_t)b * 3 * NPTS;
  const float* __restrict__ py = px + NPTS;
  const float* __restrict__ pz = py + NPTS;

  float2 z2[FPAIRS], dist2[FPAIRS];
#pragma unroll
  for (int j = 0; j < FPAIRS; ++j) {
    const int i2 = (j << 11) + (t << 1);          // point pair (i2, i2+1)
    X2[(j << 10) + t] = *(const float2*)&px[i2];
    Y2[(j << 10) + t] = *(const float2*)&py[i2];
    z2[j] = *(const float2*)&pz[i2];
    dist2[j] = make_float2(1e10f, 1e10f);
  }
  if (t == 0) fps_idx[b * FPS_N] = 0;
  float bx = px[0], by = py[0], bz = pz[0];
  const int wS = __builtin_amdgcn_readfirstlane(t >> 6);  // wave id (uniform)
  __syncthreads();

  for (int step = 1; step < FPS_N; ++step) {
    // pre-negated centroid splats: x + (-bx) == x - bx exactly (IEEE)
    const float nbx = -bx, nby = -by, nbz = -bz;
    const float2 nbx2 = make_float2(nbx, nbx);
    const float2 nby2 = make_float2(nby, nby);
    const float2 nbz2 = make_float2(nbz, nbz);
    float run = -1.0f;
#pragma unroll
    for (int j = 0; j < FPAIRS; ++j) {
      const float2 Xp = X2[(j << 10) + t];   // ds_read_b64, conflict-free
      const float2 Yp = Y2[(j << 10) + t];
      float2 t0, t1, t2;
      // exact per-element: d = ((x-bx)^2 + (y-by)^2) + (z-bz)^2, rn rounding
      asm("v_pk_add_f32 %0, %3, %6\n\t"
          "v_pk_add_f32 %1, %4, %7\n\t"
          "v_pk_add_f32 %2, %5, %8\n\t"
          "v_pk_mul_f32 %0, %0, %0\n\t"
          "v_pk_mul_f32 %1, %1, %1\n\t"
          "v_pk_mul_f32 %2, %2, %2\n\t"
          "v_pk_add_f32 %0, %0, %1\n\t"
          "v_pk_add_f32 %0, %0, %2"
          : "=&v"(t0), "=&v"(t1), "=&v"(t2)
          : "v"(Xp), "v"(Yp), "v"(z2[j]), "v"(nbx2), "v"(nby2), "v"(nbz2));
      dist2[j].x = fminf(dist2[j].x, t0.x);
      dist2[j].y = fminf(dist2[j].y, t0.y);
      asm("v_max3_f32 %0, %0, %1, %2"
          : "+v"(run) : "v"(dist2[j].x), "v"(dist2[j].y));
    }
    // wave max of dist value as u32 bit-max (dist >= 0 -> order-preserving)
    uint32_t m = __float_as_uint(run);
    {
      uint32_t s;
      s = (uint32_t)__builtin_amdgcn_update_dpp((int)m, (int)m, CTRL_XOR1, 0xf, 0xf, false); m = m > s ? m : s;
      s = (uint32_t)__builtin_amdgcn_update_dpp((int)m, (int)m, CTRL_XOR2, 0xf, 0xf, false); m = m > s ? m : s;
      s = (uint32_t)__builtin_amdgcn_update_dpp((int)m, (int)m, CTRL_ROR4, 0xf, 0xf, false); m = m > s ? m : s;
      s = (uint32_t)__builtin_amdgcn_update_dpp((int)m, (int)m, CTRL_ROR8, 0xf, 0xf, false); m = m > s ? m : s;
      s = (uint32_t)__builtin_amdgcn_ds_swizzle((int)m, 0x401f);                              m = m > s ? m : s;
      s = (uint32_t)__shfl_xor((int)m, 32, 64);                                              m = m > s ? m : s;
    }
    const float gmaxf = __uint_as_float(m);
    // index resolution: ballot + SALU ctz -> min idx achieving gmax (first-argmax)
    uint32_t widx_w = 0xFFFFFFFFu;
#pragma unroll
    for (int j = 0; j < FPAIRS; ++j) {
      const unsigned long long b0 = __ballot(dist2[j].x == gmaxf);
      const unsigned long long b1 = __ballot(dist2[j].y == gmaxf);
      const unsigned long long cb = b0 | b1;
      if (cb) {  // uniform branch (SGPR)
        const int l = (int)__builtin_ctzll(cb);
        const uint32_t p = ((b0 >> l) & 1ull) ? 0u : 1u;
        const uint32_t cand = ((uint32_t)j << 11) + ((uint32_t)((wS << 6) | l) << 1) + p;
        widx_w = widx_w < cand ? widx_w : cand;
      }
    }
    const unsigned long long key =
        ((unsigned long long)m << 32) | (uint32_t)(~widx_w);
    const int par = step & 1;
    if ((t & 63) == 0) waveres[par * 16 + wS] = key;
    __syncthreads();
    unsigned long long g = waveres[par * 16 + (t & 15)];
    DPP_MAX64(g, CTRL_XOR1);
    DPP_MAX64(g, CTRL_XOR2);
    DPP_MAX64(g, CTRL_ROR4);
    DPP_MAX64(g, CTRL_ROR8);
    const uint32_t widx = ~(uint32_t)g;
    if (t == 0) fps_idx[b * FPS_N + step] = (int)widx;
    const int si = __builtin_amdgcn_readfirstlane((int)widx);
    bx = px[si]; by = py[si]; bz = pz[si];   // scalar (uniform) loads
  }
}

// ---------------- ball-radius counts for the 50 anchors ---------------------
__global__ __launch_bounds__(256) void count_kernel(const float* __restrict__ pts,
                                                    const int* __restrict__ fps_idx,
                                                    int* __restrict__ counts) {
  const int b = blockIdx.y, a = blockIdx.x;
  const int tid = threadIdx.x;
  const float* __restrict__ px = pts + (size_t)b * 3 * NPTS;
  const float* __restrict__ py = px + NPTS;
  const float* __restrict__ pz = py + NPTS;
  const int aidx = fps_idx[b * FPS_N + a];
  const float ax = px[aidx], ay = py[aidx], az = pz[aidx];
  const float asum = __fadd_rn(__fadd_rn(__fmul_rn(ax, ax), __fmul_rn(ay, ay)),
                               __fmul_rn(az, az));
  const float R2 = (float)(0.4 * 0.4);
  int cnt = 0;
  for (int i = tid; i < NPTS; i += 256) {
    const float X = px[i], Y = py[i], Z = pz[i];
    const float dot = __fadd_rn(__fadd_rn(__fmul_rn(ax, X), __fmul_rn(ay, Y)),
                                __fmul_rn(az, Z));
    const float psum = __fadd_rn(__fadd_rn(__fmul_rn(X, X), __fmul_rn(Y, Y)),
                                 __fmul_rn(Z, Z));
    const float d = __fadd_rn(__fadd_rn(__fmul_rn(-2.0f, dot), asum), psum);
    cnt += (d < R2) ? 1 : 0;
  }
#pragma unroll
  for (int off = 32; off > 0; off >>= 1) cnt += __shfl_xor(cnt, off, 64);
  __shared__ int ws[4];
  if ((tid & 63) == 0) ws[tid >> 6] = cnt;
  __syncthreads();
  if (tid == 0) {
    int c = ws[0] + ws[1] + ws[2] + ws[3];
    counts[b * NANCH + a] = c < BALLK ? c : BALLK;
  }
}

// ---------------- top-4 anchors by count (ties -> lowest anchor index) ------
__global__ void top4_kernel(const int* __restrict__ counts,
                            const int* __restrict__ fps_idx,
                            int* __restrict__ top4pt) {
  const int b = threadIdx.x;
  if (b >= BATCH) return;
  unsigned long long used = 0ULL;
  for (int r = 0; r < TOPK; ++r) {
    int bestc = -1, besta = 0;
    for (int a = 0; a < NANCH; ++a) {
      if (used & (1ULL << a)) continue;
      const int c = counts[b * NANCH + a];
      if (c > bestc) { bestc = c; besta = a; }   // strict > keeps lowest index on ties
    }
    used |= 1ULL << besta;
    top4pt[b * TOPK + r] = fps_idx[b * FPS_N + besta];
  }
}

// ---------------- 128-NN per selected anchor, in sorted order ---------------
#define KT 1024
#define KPPT (NPTS / KT)  // 16

__device__ __forceinline__ uint32_t f2key(float f) {
  uint32_t u = __float_as_uint(f);
  return (u & 0x80000000u) ? ~u : (u | 0x80000000u);
}

__global__ __launch_bounds__(KT) void knn_kernel(const float* __restrict__ pts,
                                                 const int* __restrict__ top4pt,
                                                 int* __restrict__ nn_idx) {
  const int b = blockIdx.y, j = blockIdx.x;
  const int tid = threadIdx.x;
  const float* __restrict__ px = pts + (size_t)b * 3 * NPTS;
  const float* __restrict__ py = px + NPTS;
  const float* __restrict__ pz = py + NPTS;
  const int aidx = top4pt[b * TOPK + j];
  const float ax = px[aidx], ay = py[aidx], az = pz[aidx];
  const float asum = __fadd_rn(__fadd_rn(__fmul_rn(ax, ax), __fmul_rn(ay, ay)),
                               __fmul_rn(az, az));
  unsigned long long key[KPPT];
#pragma unroll
  for (int k = 0; k < KPPT; ++k) {
    const int i = tid + k * KT;
    const float X = px[i], Y = py[i], Z = pz[i];
    const float dot = __fadd_rn(__fadd_rn(__fmul_rn(ax, X), __fmul_rn(ay, Y)),
                                __fmul_rn(az, Z));
    const float psum = __fadd_rn(__fadd_rn(__fmul_rn(X, X), __fmul_rn(Y, Y)),
                                 __fmul_rn(Z, Z));
    const float d = __fadd_rn(__fadd_rn(__fmul_rn(-2.0f, dot), asum), psum);
    key[k] = ((unsigned long long)f2key(d) << 32) | (uint32_t)i;  // asc dist, ties asc idx
  }
  __shared__ unsigned long long waveres[2][16];
  for (int t = 0; t < NBH; ++t) {
    unsigned long long m01 = key[0] < key[1] ? key[0] : key[1];
    unsigned long long m23 = key[2] < key[3] ? key[2] : key[3];
    unsigned long long m45 = key[4] < key[5] ? key[4] : key[5];
    unsigned long long m67 = key[6] < key[7] ? key[6] : key[7];
    unsigned long long m89 = key[8] < key[9] ? key[8] : key[9];
    unsigned long long mab = key[10] < key[11] ? key[10] : key[11];
    unsigned long long mcd = key[12] < key[13] ? key[12] : key[13];
    unsigned long long mef = key[14] < key[15] ? key[14] : key[15];
    unsigned long long m0 = m01 < m23 ? m01 : m23;
    unsigned long long m1 = m45 < m67 ? m45 : m67;
    unsigned long long m2 = m89 < mab ? m89 : mab;
    unsigned long long m3 = mcd < mef ? mcd : mef;
    unsigned long long ma = m0 < m1 ? m0 : m1;
    unsigned long long mb = m2 < m3 ? m2 : m3;
    unsigned long long m = ma < mb ? ma : mb;

    DPP_MIN64(m, CTRL_XOR1);
    DPP_MIN64(m, CTRL_XOR2);
    DPP_MIN64(m, CTRL_ROR4);
    DPP_MIN64(m, CTRL_ROR8);
    SWZ16_MIN64(m);
    SHF32_MIN64(m);

    const int par = t & 1;
    if ((tid & 63) == 0) waveres[par][tid >> 6] = m;
    __syncthreads();
    unsigned long long g = waveres[par][tid & 15];
    DPP_MIN64(g, CTRL_XOR1);
    DPP_MIN64(g, CTRL_XOR2);
    DPP_MIN64(g, CTRL_ROR4);
    DPP_MIN64(g, CTRL_ROR8);

    if (tid == 0) nn_idx[(b * TOPK + j) * NBH + t] = (int)(uint32_t)g;
#pragma unroll
    for (int k = 0; k < KPPT; ++k)
      if (key[k] == g) key[k] = ~0ULL;  // remove winner (unique low bits)
  }
}

// ---------------- final gather: [roi, roi, fps_pts] -> out [16,1536,3] ------
__global__ __launch_bounds__(512) void gather_kernel(const float* __restrict__ pts,
                                                     const int* __restrict__ nn_idx,
                                                     const int* __restrict__ fps_idx,
                                                     float* __restrict__ out) {
  const int b = blockIdx.x, t = threadIdx.x;
  const float* __restrict__ px = pts + (size_t)b * 3 * NPTS;
  const float* __restrict__ py = px + NPTS;
  const float* __restrict__ pz = py + NPTS;
  for (int s = t; s < 1536; s += 512) {
    int src;
    if (s < 1024) src = nn_idx[b * 512 + (s & 511)];      // roi1 and roi2 identical
    else          src = fps_idx[b * FPS_N + (s - 1024)];
    float* o = out + ((size_t)b * 1536 + s) * 3;
    o[0] = px[src]; o[1] = py[src]; o[2] = pz[src];
  }
}

extern "C" void kernel_launch(void* const* d_in, const int* in_sizes, int n_in,
                              void* d_out, int out_size, void* d_ws, size_t ws_size,
                              hipStream_t stream) {
  const float* pts = (const float*)d_in[0];   // [16, 3, 16384]
  float* out = (float*)d_out;                 // [16, 1536, 3]
  char* ws = (char*)d_ws;
  int* fps_idx = (int*)(ws);            // 16*512*4 = 32768 B
  int* counts  = (int*)(ws + 32768);    // 16*50*4  =  3200 B
  int* top4pt  = (int*)(ws + 40960);    // 16*4*4   =   256 B
  int* nn_idx  = (int*)(ws + 49152);    // 16*512*4 = 32768 B

  hipFuncSetAttribute((const void*)fps_kernel,
                      hipFuncAttributeMaxDynamicSharedMemorySize, FPS_SMEM);

  fps_kernel<<<dim3(BATCH), dim3(FT), FPS_SMEM, stream>>>(pts, fps_idx);
  count_kernel<<<dim3(NANCH, BATCH), dim3(256), 0, stream>>>(pts, fps_idx, counts);
  top4_kernel<<<dim3(1), dim3(64), 0, stream>>>(counts, fps_idx, top4pt);
  knn_kernel<<<dim3(TOPK, BATCH), dim3(KT), 0, stream>>>(pts, top4pt, nn_idx);
  gather_kernel<<<dim3(BATCH), dim3(512), 0, stream>>>(pts, nn_idx, fps_idx, out);
}

// Round 6
// 987.205 us; speedup vs baseline: 1.1331x; 1.0867x over previous
//
#include <hip/hip_runtime.h>
#include <stdint.h>

#define NPTS 16384
#define BATCH 16
#define FPS_N 512
#define NANCH 50
#define TOPK 4
#define NBH 128
#define BALLK 1000

#define FT 512          // threads per block (8 waves)
#define PAIRS 16        // float2 point-pairs per thread (32 pts)

// ---- dynamic LDS layout (bytes) ----
#define OFF_X2 0                         // 8192 float2 = 65536
#define OFF_Y2 65536                     // 8192 float2 = 65536
#define OFF_FPSIDX 131072                // 512 int    = 2048
#define OFF_CNT    (OFF_FPSIDX + 2048)   // 64 int     = 256
#define OFF_WRED   (OFF_CNT + 256)       // 2*8 u64    = 128
#define OFF_T4     (OFF_WRED + 128)      // 4 int      = 16
#define OFF_KNN    (OFF_T4 + 16)         // 128 int    = 512
#define SMEM_TOTAL (OFF_KNN + 512)       // 134032 B

// DPP controls
#define CTRL_XOR1 0xB1
#define CTRL_XOR2 0x4E
#define CTRL_ROR4 0x124
#define CTRL_ROR8 0x128

#define DPP_MAX64(v, CTRL) do {                                                   \
  unsigned int _lo = (unsigned int)(v);                                           \
  unsigned int _hi = (unsigned int)((v) >> 32);                                   \
  unsigned int _slo = (unsigned int)__builtin_amdgcn_update_dpp((int)_lo, (int)_lo, CTRL, 0xf, 0xf, false); \
  unsigned int _shi = (unsigned int)__builtin_amdgcn_update_dpp((int)_hi, (int)_hi, CTRL, 0xf, 0xf, false); \
  unsigned long long _o = (((unsigned long long)_shi) << 32) | _slo;              \
  if (_o > (v)) (v) = _o;                                                         \
} while (0)

#define DPP_MIN64(v, CTRL) do {                                                   \
  unsigned int _lo = (unsigned int)(v);                                           \
  unsigned int _hi = (unsigned int)((v) >> 32);                                   \
  unsigned int _slo = (unsigned int)__builtin_amdgcn_update_dpp((int)_lo, (int)_lo, CTRL, 0xf, 0xf, false); \
  unsigned int _shi = (unsigned int)__builtin_amdgcn_update_dpp((int)_hi, (int)_hi, CTRL, 0xf, 0xf, false); \
  unsigned long long _o = (((unsigned long long)_shi) << 32) | _slo;              \
  if (_o < (v)) (v) = _o;                                                         \
} while (0)

#define SWZ16_MIN64(v) do {                                                       \
  unsigned int _lo = (unsigned int)(v), _hi = (unsigned int)((v) >> 32);          \
  unsigned int _slo = (unsigned int)__builtin_amdgcn_ds_swizzle((int)_lo, 0x401f);\
  unsigned int _shi = (unsigned int)__builtin_amdgcn_ds_swizzle((int)_hi, 0x401f);\
  unsigned long long _o = (((unsigned long long)_shi) << 32) | _slo;              \
  if (_o < (v)) (v) = _o;                                                         \
} while (0)

#define SHF32_MIN64(v) do {                                                       \
  unsigned long long _o = __shfl_xor((v), 32, 64);                                \
  if (_o < (v)) (v) = _o;                                                         \
} while (0)

__device__ __forceinline__ uint32_t f2key(float f) {
  uint32_t u = __float_as_uint(f);
  return (u & 0x80000000u) ? ~u : (u | 0x80000000u);
}

// One fused kernel. Blocks 0..15: full 512-step FPS for batch b + fps output.
// Blocks 16..79 (b,j): redundant 50-step seed FPS (bit-identical), ball counts,
// top4, the j-th anchor's 128-NN, roi1+roi2 output. No cross-block comms.
__global__ __launch_bounds__(FT, 2) void mega_kernel(const float* __restrict__ pts,
                                                     float* __restrict__ out) {
  extern __shared__ char smem[];
  float2* __restrict__ X2 = (float2*)(smem + OFF_X2);
  float2* __restrict__ Y2 = (float2*)(smem + OFF_Y2);
  int* __restrict__ fpsidx = (int*)(smem + OFF_FPSIDX);
  int* __restrict__ cnt = (int*)(smem + OFF_CNT);
  unsigned long long* __restrict__ wred = (unsigned long long*)(smem + OFF_WRED);
  int* __restrict__ t4 = (int*)(smem + OFF_T4);
  int* __restrict__ knnidx = (int*)(smem + OFF_KNN);

  const int bid = blockIdx.x;
  const bool isFps = bid < BATCH;
  const int b = isFps ? bid : ((bid - BATCH) >> 2);
  const int j = isFps ? 0 : ((bid - BATCH) & 3);
  const int nsteps = isFps ? FPS_N : NANCH;

  const int t = threadIdx.x;
  const int wS = __builtin_amdgcn_readfirstlane(t >> 6);  // wave id 0..7
  const float* __restrict__ px = pts + (size_t)b * 3 * NPTS;
  const float* __restrict__ py = px + NPTS;
  const float* __restrict__ pz = py + NPTS;

  // ---- stage coords: xy -> LDS, z + dist -> registers ----
  float2 z2[PAIRS], dist2[PAIRS];
#pragma unroll
  for (int k = 0; k < PAIRS; ++k) {
    const int i2 = (k << 10) + (t << 1);
    X2[(k << 9) + t] = *(const float2*)&px[i2];
    Y2[(k << 9) + t] = *(const float2*)&py[i2];
    z2[k] = *(const float2*)&pz[i2];
    dist2[k] = make_float2(1e10f, 1e10f);
  }
  if (t == 0) fpsidx[0] = 0;
  float bx = px[0], by = py[0], bz = pz[0];
  __syncthreads();

  // ---- FPS loop (identical code for both roles -> bit-identical seeds) ----
  for (int step = 1; step < nsteps; ++step) {
    const float nbx = -bx, nby = -by, nbz = -bz;
    const float2 nbx2 = make_float2(nbx, nbx);
    const float2 nby2 = make_float2(nby, nby);
    const float2 nbz2 = make_float2(nbz, nbz);
    float run = -1.0f;
#pragma unroll
    for (int k = 0; k < PAIRS; ++k) {
      const float2 Xp = X2[(k << 9) + t];
      const float2 Yp = Y2[(k << 9) + t];
      float2 t0, t1, t2;
      // exact: d = ((x-bx)^2 + (y-by)^2) + (z-bz)^2, rn (x + (-bx) == x - bx)
      asm("v_pk_add_f32 %0, %3, %6\n\t"
          "v_pk_add_f32 %1, %4, %7\n\t"
          "v_pk_add_f32 %2, %5, %8\n\t"
          "v_pk_mul_f32 %0, %0, %0\n\t"
          "v_pk_mul_f32 %1, %1, %1\n\t"
          "v_pk_mul_f32 %2, %2, %2\n\t"
          "v_pk_add_f32 %0, %0, %1\n\t"
          "v_pk_add_f32 %0, %0, %2"
          : "=&v"(t0), "=&v"(t1), "=&v"(t2)
          : "v"(Xp), "v"(Yp), "v"(z2[k]), "v"(nbx2), "v"(nby2), "v"(nbz2));
      dist2[k].x = fminf(dist2[k].x, t0.x);
      dist2[k].y = fminf(dist2[k].y, t0.y);
      asm("v_max3_f32 %0, %0, %1, %2"
          : "+v"(run) : "v"(dist2[k].x), "v"(dist2[k].y));
    }
    // wave max of value (u32 bit-order ok: dist >= 0)
    uint32_t m = __float_as_uint(run);
    {
      uint32_t s;
      s = (uint32_t)__builtin_amdgcn_update_dpp((int)m, (int)m, CTRL_XOR1, 0xf, 0xf, false); m = m > s ? m : s;
      s = (uint32_t)__builtin_amdgcn_update_dpp((int)m, (int)m, CTRL_XOR2, 0xf, 0xf, false); m = m > s ? m : s;
      s = (uint32_t)__builtin_amdgcn_update_dpp((int)m, (int)m, CTRL_ROR4, 0xf, 0xf, false); m = m > s ? m : s;
      s = (uint32_t)__builtin_amdgcn_update_dpp((int)m, (int)m, CTRL_ROR8, 0xf, 0xf, false); m = m > s ? m : s;
      s = (uint32_t)__builtin_amdgcn_ds_swizzle((int)m, 0x401f);                              m = m > s ? m : s;
      s = (uint32_t)__shfl_xor((int)m, 32, 64);                                              m = m > s ? m : s;
    }
    const float gmaxf = __uint_as_float(m);
    // index resolution: ballot + SALU ctz -> lowest idx achieving the max
    uint32_t widx_w = 0xFFFFFFFFu;
#pragma unroll
    for (int k = 0; k < PAIRS; ++k) {
      const unsigned long long b0 = __ballot(dist2[k].x == gmaxf);
      const unsigned long long b1 = __ballot(dist2[k].y == gmaxf);
      const unsigned long long cb = b0 | b1;
      if (cb) {
        const int l = (int)__builtin_ctzll(cb);
        const uint32_t p = ((b0 >> l) & 1ull) ? 0u : 1u;
        const uint32_t cand = ((uint32_t)k << 10) + ((uint32_t)((wS << 6) | l) << 1) + p;
        widx_w = widx_w < cand ? widx_w : cand;
      }
    }
    const unsigned long long key =
        ((unsigned long long)m << 32) | (uint32_t)(~widx_w);
    const int par = step & 1;
    if ((t & 63) == 0) wred[par * 8 + wS] = key;
    __syncthreads();
    unsigned long long g = wred[par * 8 + (t & 7)];
    DPP_MAX64(g, CTRL_XOR1);
    DPP_MAX64(g, CTRL_XOR2);
    DPP_MAX64(g, CTRL_ROR4);
    const uint32_t widx = ~(uint32_t)g;
    if (t == 0) fpsidx[step] = (int)widx;
    const int si = __builtin_amdgcn_readfirstlane((int)widx);
    bx = px[si]; by = py[si]; bz = pz[si];
  }

  if (isFps) {
    // ---- write fps_pts slice: out[b, 1024+s, :] ----
    __syncthreads();
    const int idx = fpsidx[t];
    const float X = px[idx], Y = py[idx], Z = pz[idx];
    float* o = out + ((size_t)b * 1536 + 1024 + t) * 3;
    o[0] = X; o[1] = Y; o[2] = Z;
    return;
  }

  // ================= worker path =================
  const float R2 = (float)(0.4 * 0.4);

  // ---- ball counts for the 50 seed anchors ----
  if (t < 64) cnt[t] = 0;
  __syncthreads();
  for (int a = 0; a < NANCH; ++a) {
    const int ai = fpsidx[a];
    const float ax = px[ai], ay = py[ai], az = pz[ai];
    const float asum = __fadd_rn(__fadd_rn(__fmul_rn(ax, ax), __fmul_rn(ay, ay)),
                                 __fmul_rn(az, az));
    int local = 0;
#pragma unroll
    for (int k = 0; k < PAIRS; ++k) {
      const float2 Xp = X2[(k << 9) + t];
      const float2 Yp = Y2[(k << 9) + t];
      const float2 Zp = z2[k];
      {
        const float dot = __fadd_rn(__fadd_rn(__fmul_rn(ax, Xp.x), __fmul_rn(ay, Yp.x)),
                                    __fmul_rn(az, Zp.x));
        const float ps = __fadd_rn(__fadd_rn(__fmul_rn(Xp.x, Xp.x), __fmul_rn(Yp.x, Yp.x)),
                                   __fmul_rn(Zp.x, Zp.x));
        const float d = __fadd_rn(__fadd_rn(__fmul_rn(-2.0f, dot), asum), ps);
        local += (d < R2) ? 1 : 0;
      }
      {
        const float dot = __fadd_rn(__fadd_rn(__fmul_rn(ax, Xp.y), __fmul_rn(ay, Yp.y)),
                                    __fmul_rn(az, Zp.y));
        const float ps = __fadd_rn(__fadd_rn(__fmul_rn(Xp.y, Xp.y), __fmul_rn(Yp.y, Yp.y)),
                                   __fmul_rn(Zp.y, Zp.y));
        const float d = __fadd_rn(__fadd_rn(__fmul_rn(-2.0f, dot), asum), ps);
        local += (d < R2) ? 1 : 0;
      }
    }
#pragma unroll
    for (int off = 32; off > 0; off >>= 1) local += __shfl_xor(local, off, 64);
    if ((t & 63) == 0) atomicAdd(&cnt[a], local);
  }
  __syncthreads();

  // ---- top4 anchors (ties -> lowest anchor index) ----
  if (t == 0) {
    unsigned long long used = 0ULL;
    for (int r = 0; r < TOPK; ++r) {
      int bestc = -1, besta = 0;
      for (int a = 0; a < NANCH; ++a) {
        if (used & (1ULL << a)) continue;
        int c = cnt[a];
        c = c < BALLK ? c : BALLK;
        if (c > bestc) { bestc = c; besta = a; }
      }
      used |= 1ULL << besta;
      t4[r] = fpsidx[besta];
    }
  }
  __syncthreads();

  // ---- 128-NN for my anchor j (sorted ascending dist, ties ascending idx) ----
  const int ai = t4[j];
  const float ax = px[ai], ay = py[ai], az = pz[ai];
  const float asum = __fadd_rn(__fadd_rn(__fmul_rn(ax, ax), __fmul_rn(ay, ay)),
                               __fmul_rn(az, az));
  unsigned long long kk[2 * PAIRS];
#pragma unroll
  for (int k = 0; k < PAIRS; ++k) {
    const int i2 = (k << 10) + (t << 1);
    const float2 Xp = X2[(k << 9) + t];
    const float2 Yp = Y2[(k << 9) + t];
    const float2 Zp = z2[k];
    {
      const float dot = __fadd_rn(__fadd_rn(__fmul_rn(ax, Xp.x), __fmul_rn(ay, Yp.x)),
                                  __fmul_rn(az, Zp.x));
      const float ps = __fadd_rn(__fadd_rn(__fmul_rn(Xp.x, Xp.x), __fmul_rn(Yp.x, Yp.x)),
                                 __fmul_rn(Zp.x, Zp.x));
      const float d = __fadd_rn(__fadd_rn(__fmul_rn(-2.0f, dot), asum), ps);
      kk[2 * k] = ((unsigned long long)f2key(d) << 32) | (uint32_t)i2;
    }
    {
      const float dot = __fadd_rn(__fadd_rn(__fmul_rn(ax, Xp.y), __fmul_rn(ay, Yp.y)),
                                  __fmul_rn(az, Zp.y));
      const float ps = __fadd_rn(__fadd_rn(__fmul_rn(Xp.y, Xp.y), __fmul_rn(Yp.y, Yp.y)),
                                 __fmul_rn(Zp.y, Zp.y));
      const float d = __fadd_rn(__fadd_rn(__fmul_rn(-2.0f, dot), asum), ps);
      kk[2 * k + 1] = ((unsigned long long)f2key(d) << 32) | (uint32_t)(i2 + 1);
    }
  }
  for (int r = 0; r < NBH; ++r) {
    // tree-min over 32 register keys (static indices after unroll)
    unsigned long long v16[16];
#pragma unroll
    for (int k = 0; k < 16; ++k) v16[k] = kk[2 * k] < kk[2 * k + 1] ? kk[2 * k] : kk[2 * k + 1];
#pragma unroll
    for (int k = 0; k < 8; ++k) v16[k] = v16[k] < v16[k + 8] ? v16[k] : v16[k + 8];
#pragma unroll
    for (int k = 0; k < 4; ++k) v16[k] = v16[k] < v16[k + 4] ? v16[k] : v16[k + 4];
    unsigned long long m0 = v16[0] < v16[2] ? v16[0] : v16[2];
    unsigned long long m1 = v16[1] < v16[3] ? v16[1] : v16[3];
    unsigned long long m = m0 < m1 ? m0 : m1;

    DPP_MIN64(m, CTRL_XOR1);
    DPP_MIN64(m, CTRL_XOR2);
    DPP_MIN64(m, CTRL_ROR4);
    DPP_MIN64(m, CTRL_ROR8);
    SWZ16_MIN64(m);
    SHF32_MIN64(m);

    const int par = r & 1;
    if ((t & 63) == 0) wred[par * 8 + wS] = m;
    __syncthreads();
    unsigned long long g = wred[par * 8 + (t & 7)];
    DPP_MIN64(g, CTRL_XOR1);
    DPP_MIN64(g, CTRL_XOR2);
    DPP_MIN64(g, CTRL_ROR4);
    if (t == 0) knnidx[r] = (int)(uint32_t)g;
#pragma unroll
    for (int k = 0; k < 2 * PAIRS; ++k)
      if (kk[k] == g) kk[k] = ~0ULL;  // remove winner (unique low bits)
  }
  __syncthreads();

  // ---- write roi1 and roi2 slices: out[b, j*128+s, :] and out[b, 512+j*128+s, :]
  if (t < NBH) {
    const int idx = knnidx[t];
    const float X = px[idx], Y = py[idx], Z = pz[idx];
    float* o1 = out + ((size_t)b * 1536 + (j << 7) + t) * 3;
    float* o2 = o1 + 512 * 3;
    o1[0] = X; o1[1] = Y; o1[2] = Z;
    o2[0] = X; o2[1] = Y; o2[2] = Z;
  }
}

extern "C" void kernel_launch(void* const* d_in, const int* in_sizes, int n_in,
                              void* d_out, int out_size, void* d_ws, size_t ws_size,
                              hipStream_t stream) {
  const float* pts = (const float*)d_in[0];   // [16, 3, 16384]
  float* out = (float*)d_out;                 // [16, 1536, 3]
  (void)d_ws; (void)ws_size;

  hipFuncSetAttribute((const void*)mega_kernel,
                      hipFuncAttributeMaxDynamicSharedMemorySize, SMEM_TOTAL);
  mega_kernel<<<dim3(BATCH + BATCH * TOPK), dim3(FT), SMEM_TOTAL, stream>>>(pts, out);
}